// Round 3
// baseline (372.859 us; speedup 1.0000x reference)
//
#include <hip/hip_runtime.h>

// VQGAN VectorQuantizer forward.
// z: (32,256,32,32) f32, emb: (1024,256) f32.
// d_out (float): [0..8388607] z_q (b,c,h,w) | [8388608] loss | [8388609..] indices.
//
// The harness's np reference computes d = (||z||^2 + ||e||^2) - 2*z.e in FLOAT32,
// so scores are quantized to ulp(~256) ~ 3e-5. We replicate that quantization:
//   t1 = fl32(A_n + B_k);  d = fl32(t1 - 2*dot)   (fma = single rounding, same as np)
// A_n's exact bits don't matter (same-binade f32 delta shifts all scores of a row
// by an exact ulp-grid multiple -> argmin invariant); B/dot ambiguity ~1e-8 << grid.
// Ties on the quantized grid -> lowest index (np.argmin first-occurrence).
//
// Scratch stashed in the z_q region of d_out (dead until k_gather overwrites it):
//   out[0..1023]           : B_k = ||emb_k||^2
//   out[2048..2048+32767]  : A_n = ||z_n||^2
// d_ws unused.

#define DDIM 256
#define LOSS_OFF 8388608
#define IDX_OFF 8388609
#define A_BASE 2048

// ---------------- kernel A1: B_k = ||emb_k||^2 ; zero loss ----------------
__global__ __launch_bounds__(256) void k_enorm(const float* __restrict__ emb,
                                               float* __restrict__ out) {
  const int tid = threadIdx.x;
  if (blockIdx.x == 0 && tid == 0) out[LOSS_OFF] = 0.0f;
  const int lane = tid & 63;
  const int row = blockIdx.x * 4 + (tid >> 6);
  const float4 v = *(const float4*)(emb + row * DDIM + lane * 4);
  float s = v.x * v.x + v.y * v.y + v.z * v.z + v.w * v.w;
#pragma unroll
  for (int off = 32; off; off >>= 1) s += __shfl_down(s, off);
  if (lane == 0) out[row] = s;
}

// ---------------- kernel A2: A_n = ||z_n||^2 ----------------
// One thread per row n; d-loop loads are coalesced across threads (consecutive
// n -> consecutive hw). 8 accumulators + tree: error ~1e-5, binade-safe.
__global__ __launch_bounds__(256) void k_znorm(const float* __restrict__ z,
                                               float* __restrict__ out) {
  const int n = blockIdx.x * 256 + threadIdx.x;  // 0..32767
  const int b = n >> 10, hw = n & 1023;
  const float* p = z + b * 262144 + hw;
  float a[8] = {0.f, 0.f, 0.f, 0.f, 0.f, 0.f, 0.f, 0.f};
  for (int d = 0; d < 256; d += 8) {
#pragma unroll
    for (int j = 0; j < 8; ++j) {
      const float v = p[(d + j) * 1024];
      a[j] = fmaf(v, v, a[j]);
    }
  }
  out[A_BASE + n] = ((a[0] + a[1]) + (a[2] + a[3])) + ((a[4] + a[5]) + (a[6] + a[7]));
}

// ---------------- kernel B: per-row argmin over 1024 codes ----------------
// 64 rows/block, 256 threads, 4x4 micro-tile; Z tile (64x256) LDS-resident
// d-major, E tiles (32d x 64k) double-buffered. Epilogue replicates the np-f32
// quantized score; ties -> lowest k.
__global__ __launch_bounds__(256) void k_argmin(const float* __restrict__ z,
                                                const float* __restrict__ emb,
                                                float* __restrict__ out) {
  __shared__ float Zs[DDIM][64];     // 64 KB, Zs[d][m]
  __shared__ float Es[2][32][64];    // 16 KB, Es[buf][dd][kk]
  const int tid = threadIdx.x;
  const int tx = tid & 15, ty = tid >> 4;
  const int row0 = blockIdx.x * 64;

  // stage Z tile (global c-strided -> LDS d-major)
  {
    const int m4 = (tid & 15) << 2;
    const int dsub = tid >> 4;
    const int b = row0 >> 10;
    const int off = ((row0 >> 5) & 31) << 5;   // row0 mod 1024
    const float* zbase = z + b * 262144 + off;
#pragma unroll
    for (int i = 0; i < 16; ++i) {
      const int d = i * 16 + dsub;
      const float4 v = *(const float4*)(zbase + d * 1024 + m4);
      *(float4*)&Zs[d][m4] = v;
    }
  }

  auto stageE = [&](int q, int bf) {
    const int kk = tid & 63;
    const int dl = tid >> 6;
    const int k0 = (q >> 3) << 6;
    const int d0 = (q & 7) << 5;
    const float* ep = emb + (k0 + kk) * DDIM + d0 + (dl << 2);
#pragma unroll
    for (int j = 0; j < 2; ++j) {
      const float4 v = *(const float4*)(ep + j * 16);
      const int dd = (dl << 2) + j * 16;
      Es[bf][dd + 0][kk] = v.x;
      Es[bf][dd + 1][kk] = v.y;
      Es[bf][dd + 2][kk] = v.z;
      Es[bf][dd + 3][kk] = v.w;
    }
  };

  stageE(0, 0);
  __syncthreads();

  // A for this thread's 4 rows
  const float4 av4 = *(const float4*)(out + A_BASE + row0 + (ty << 2));
  const float av[4] = {av4.x, av4.y, av4.z, av4.w};

  float bv1[4] = {3.0e38f, 3.0e38f, 3.0e38f, 3.0e38f};
  int bi1[4] = {0, 0, 0, 0};

  int cur = 0;
  for (int kt = 0; kt < 16; ++kt) {
    const int k0 = kt << 6;
    const float4 bkv = *(const float4*)(out + k0 + (tx << 2));  // B_k stash
    const float bk[4] = {bkv.x, bkv.y, bkv.z, bkv.w};
    float acc[4][4] = {};
    for (int ch = 0; ch < 8; ++ch) {
      const int q = (kt << 3) + ch;
      if (q + 1 < 128) stageE(q + 1, cur ^ 1);
      const int dbase = ch << 5;
#pragma unroll 8
      for (int dd = 0; dd < 32; ++dd) {
        const float4 za4 = *(const float4*)&Zs[dbase + dd][ty << 2];
        const float4 eb4 = *(const float4*)&Es[cur][dd][tx << 2];
        const float a[4] = {za4.x, za4.y, za4.z, za4.w};
        const float e[4] = {eb4.x, eb4.y, eb4.z, eb4.w};
#pragma unroll
        for (int r = 0; r < 4; ++r)
#pragma unroll
          for (int c = 0; c < 4; ++c) acc[r][c] = fmaf(a[r], e[c], acc[r][c]);
      }
      __syncthreads();
      cur ^= 1;
    }
    // np-f32 quantized score: d = fl(fl(A+B) - 2*dot); ties -> lowest k
#pragma unroll
    for (int r = 0; r < 4; ++r) {
#pragma unroll
      for (int c = 0; c < 4; ++c) {
        const float t1 = av[r] + bk[c];
        const float s = fmaf(-2.0f, acc[r][c], t1);
        const int ki = k0 + (tx << 2) + c;
        if (s < bv1[r]) { bv1[r] = s; bi1[r] = ki; }
      }
    }
  }

  // reduce across the 16 tx lanes per row; ties -> lowest index
#pragma unroll
  for (int r = 0; r < 4; ++r) {
    float v = bv1[r];
    int id = bi1[r];
#pragma unroll
    for (int off = 1; off < 16; off <<= 1) {
      const float ov = __shfl_xor(v, off);
      const int oi = __shfl_xor(id, off);
      if (ov < v || (ov == v && oi < id)) { v = ov; id = oi; }
    }
    if (tx == 0) out[IDX_OFF + row0 + (ty << 2) + r] = (float)id;
  }
}

// ---------------- kernel C: z_q gather + loss (atomic per block) ----------------
__global__ __launch_bounds__(256) void k_gather(const float* __restrict__ z,
                                                const float* __restrict__ emb,
                                                float* __restrict__ out) {
  const int tid = threadIdx.x;
  const int e4 = (blockIdx.x * 256 + tid) * 4;
  const int b = e4 >> 18;
  const int c = (e4 >> 10) & 255;
  const int rem = e4 & 1023;
  const int n0 = (b << 10) + rem;
  const float* idxf = out + IDX_OFF;
  const float4 zv = *(const float4*)(z + e4);
  const float zz[4] = {zv.x, zv.y, zv.z, zv.w};
  float acc = 0.f;
  float q[4];
#pragma unroll
  for (int j = 0; j < 4; ++j) {
    const int id = (int)(idxf[n0 + j] + 0.5f);
    const float e = emb[id * DDIM + c];
    q[j] = e;
    const float d = e - zz[j];
    acc = fmaf(d, d, acc);
  }
  const float4 qv = {q[0], q[1], q[2], q[3]};
  *(float4*)(out + e4) = qv;

  __shared__ float sm[256];
  sm[tid] = acc;
  __syncthreads();
  for (int off = 128; off; off >>= 1) {
    if (tid < off) sm[tid] += sm[tid + off];
    __syncthreads();
  }
  if (tid == 0) atomicAdd(out + LOSS_OFF, sm[0] * (1.25f / 8388608.0f));
}

extern "C" void kernel_launch(void* const* d_in, const int* in_sizes, int n_in,
                              void* d_out, int out_size, void* d_ws, size_t ws_size,
                              hipStream_t stream) {
  const float* z = (const float*)d_in[0];
  const float* emb = (const float*)d_in[1];
  float* out = (float*)d_out;

  k_enorm<<<256, 256, 0, stream>>>(emb, out);
  k_znorm<<<128, 256, 0, stream>>>(z, out);
  k_argmin<<<512, 256, 0, stream>>>(z, emb, out);
  k_gather<<<8192, 256, 0, stream>>>(z, emb, out);
}

// Round 4
// 275.689 us; speedup vs baseline: 1.3525x; 1.3525x over previous
//
#include <hip/hip_runtime.h>

// VQGAN VectorQuantizer forward.
// z: (32,256,32,32) f32, emb: (1024,256) f32.
// d_out (float): [0..8388607] z_q (b,c,h,w) | [8388608] loss | [8388609..] indices.
//
// Numerics (carried from round 3, which passed): replicate the np-f32 quantized
// score s = fl(fl(A_n + B_k) - 2*dot) with dot = serial in-order f32 FMA over
// d=0..255 per (n,k). This round keeps every dot/epilogue bit identical; only
// the schedule changes (8x8 micro-tile, pk_fma, col-tiles in grid + exact
// first-index partial merge).
//
// Scratch in the z_q region of d_out (dead until k_gather overwrites it):
//   out[0..1023]          B_k = ||emb_k||^2
//   out[2048..34815]      A_n = ||z_n||^2
//   out[65536..327679]    pval[8][32768]  per-col-tile best score
//   out[327680..589823]   pidx[8][32768]  per-col-tile best index (as float)

#define DDIM 256
#define LOSS_OFF 8388608
#define IDX_OFF 8388609
#define A_BASE 2048
#define PVAL_BASE 65536
#define PIDX_BASE 327680

typedef float f32x2 __attribute__((ext_vector_type(2)));

// ---------------- kernel A1: B_k = ||emb_k||^2 ; zero loss ----------------
__global__ __launch_bounds__(256) void k_enorm(const float* __restrict__ emb,
                                               float* __restrict__ out) {
  const int tid = threadIdx.x;
  if (blockIdx.x == 0 && tid == 0) out[LOSS_OFF] = 0.0f;
  const int lane = tid & 63;
  const int row = blockIdx.x * 4 + (tid >> 6);
  const float4 v = *(const float4*)(emb + row * DDIM + lane * 4);
  float s = v.x * v.x + v.y * v.y + v.z * v.z + v.w * v.w;
#pragma unroll
  for (int off = 32; off; off >>= 1) s += __shfl_down(s, off);
  if (lane == 0) out[row] = s;
}

// ---------------- kernel A2: A_n = ||z_n||^2 (bit-identical to round 3) ----
__global__ __launch_bounds__(256) void k_znorm(const float* __restrict__ z,
                                               float* __restrict__ out) {
  const int n = blockIdx.x * 256 + threadIdx.x;  // 0..32767
  const int b = n >> 10, hw = n & 1023;
  const float* p = z + b * 262144 + hw;
  float a[8] = {0.f, 0.f, 0.f, 0.f, 0.f, 0.f, 0.f, 0.f};
  for (int d = 0; d < 256; d += 8) {
#pragma unroll
    for (int j = 0; j < 8; ++j) {
      const float v = p[(d + j) * 1024];
      a[j] = fmaf(v, v, a[j]);
    }
  }
  out[A_BASE + n] = ((a[0] + a[1]) + (a[2] + a[3])) + ((a[4] + a[5]) + (a[6] + a[7]));
}

// ---------------- kernel B: scores + per-tile argmin ----------------
// Block: 128 rows x 128 cols. 256 threads (tx 0..15 col-groups, ty 0..15
// row-groups), 8x8 micro-tile via v_pk_fma_f32. d staged in 16-deep chunks,
// double-buffered, load/write split so HBM latency hides under compute.
// grid.x = ct*256 + rt (ct = col-tile 0..7, rt = row-tile 0..255).
__global__ __launch_bounds__(256, 3) void k_score(const float* __restrict__ z,
                                                  const float* __restrict__ emb,
                                                  float* __restrict__ out) {
  __shared__ float Zs[2][16][128];   // 16 KB: Zs[buf][dd][m]
  __shared__ float Es[2][16][128];   // 16 KB: Es[buf][dd][kk]
  const int tid = threadIdx.x;
  const int tx = tid & 15, ty = tid >> 4;
  const int rt = blockIdx.x & 255;
  const int ct = blockIdx.x >> 8;
  const int row0 = rt << 7;          // 128 rows, never crosses b (128 | 1024)
  const int k0 = ct << 7;            // 128 codes
  const float* zbase = z + (row0 >> 10) * 262144 + (row0 & 1023);

  // staging thread roles
  const int sm4 = (tid & 31) << 2;       // Z: m offset 0..124
  const int sdp2 = (tid >> 5) << 1;      // Z: dd base 0,2,..,14
  const int skk = tid >> 1;              // E: 0..127
  const int sdh = (tid & 1) << 3;        // E: dd half 0/8
  const float* ebase = emb + (k0 + skk) * DDIM + sdh;

  float4 pz0, pz1, pe0, pe1;
  auto stage_load = [&](int ch) {
    const int d0 = ch << 4;
    pz0 = *(const float4*)(zbase + (d0 + sdp2) * 1024 + sm4);
    pz1 = *(const float4*)(zbase + (d0 + sdp2 + 1) * 1024 + sm4);
    pe0 = *(const float4*)(ebase + d0);
    pe1 = *(const float4*)(ebase + d0 + 4);
  };
  auto stage_write = [&](int bf) {
    *(float4*)&Zs[bf][sdp2][sm4] = pz0;
    *(float4*)&Zs[bf][sdp2 + 1][sm4] = pz1;
    Es[bf][sdh + 0][skk] = pe0.x;
    Es[bf][sdh + 1][skk] = pe0.y;
    Es[bf][sdh + 2][skk] = pe0.z;
    Es[bf][sdh + 3][skk] = pe0.w;
    Es[bf][sdh + 4][skk] = pe1.x;
    Es[bf][sdh + 5][skk] = pe1.y;
    Es[bf][sdh + 6][skk] = pe1.z;
    Es[bf][sdh + 7][skk] = pe1.w;
  };

  stage_load(0);
  stage_write(0);
  __syncthreads();

  f32x2 acc[8][4];
#pragma unroll
  for (int r = 0; r < 8; ++r)
#pragma unroll
    for (int c = 0; c < 4; ++c) acc[r][c] = (f32x2){0.f, 0.f};

  const int ty8 = ty << 3, tx4 = tx << 2;
  for (int ch = 0; ch < 16; ++ch) {
    const int cur = ch & 1;
    if (ch < 15) stage_load(ch + 1);
    const float (*zc)[128] = Zs[cur];
    const float (*ec)[128] = Es[cur];
#pragma unroll
    for (int dd = 0; dd < 16; ++dd) {
      const float4 za0 = *(const float4*)&zc[dd][ty8];
      const float4 za1 = *(const float4*)&zc[dd][ty8 + 4];
      const float4 eb0 = *(const float4*)&ec[dd][tx4];
      const float4 eb1 = *(const float4*)&ec[dd][64 + tx4];
      const f32x2 bp[4] = {{eb0.x, eb0.y}, {eb0.z, eb0.w},
                           {eb1.x, eb1.y}, {eb1.z, eb1.w}};
      const float ar[8] = {za0.x, za0.y, za0.z, za0.w,
                           za1.x, za1.y, za1.z, za1.w};
#pragma unroll
      for (int r = 0; r < 8; ++r) {
        f32x2 s;
        s.x = ar[r];
        s.y = ar[r];
#pragma unroll
        for (int cq = 0; cq < 4; ++cq)
          asm("v_pk_fma_f32 %0, %1, %2, %0"
              : "+v"(acc[r][cq])
              : "v"(s), "v"(bp[cq]));
      }
    }
    if (ch < 15) stage_write(cur ^ 1);
    __syncthreads();
  }

  // epilogue: np-f32 quantized score, per-tile first-index argmin
  const float4 av0 = *(const float4*)(out + A_BASE + row0 + ty8);
  const float4 av1 = *(const float4*)(out + A_BASE + row0 + ty8 + 4);
  const float avr[8] = {av0.x, av0.y, av0.z, av0.w, av1.x, av1.y, av1.z, av1.w};
  const float4 bk0 = *(const float4*)(out + k0 + tx4);
  const float4 bk1 = *(const float4*)(out + k0 + 64 + tx4);
  const float bkv[8] = {bk0.x, bk0.y, bk0.z, bk0.w, bk1.x, bk1.y, bk1.z, bk1.w};
  const int kb0 = k0 + tx4, kb1 = k0 + 64 + tx4;

#pragma unroll
  for (int r = 0; r < 8; ++r) {
    float best = 3.0e38f;
    int bi = 0;
#pragma unroll
    for (int j = 0; j < 8; ++j) {
      const float dot = (j & 1) ? acc[r][j >> 1].y : acc[r][j >> 1].x;
      const float t1 = avr[r] + bkv[j];
      const float sc = fmaf(-2.0f, dot, t1);   // single rounding, matches np
      const int ki = (j < 4) ? (kb0 + j) : (kb1 + j - 4);
      if (sc < best) { best = sc; bi = ki; }   // strict < keeps lowest k
    }
    float v = best;
    int id = bi;
#pragma unroll
    for (int off = 1; off < 16; off <<= 1) {
      const float ov = __shfl_xor(v, off);
      const int oi = __shfl_xor(id, off);
      if (ov < v || (ov == v && oi < id)) { v = ov; id = oi; }
    }
    if (tx == 0) {
      const int row = row0 + ty8 + r;
      out[PVAL_BASE + (ct << 15) + row] = v;
      out[PIDX_BASE + (ct << 15) + row] = (float)id;
    }
  }
}

// ---------------- kernel B2: merge 8 col-tiles (exact first-index) --------
__global__ __launch_bounds__(256) void k_reduce(float* __restrict__ out) {
  const int row = blockIdx.x * 256 + threadIdx.x;
  float v = out[PVAL_BASE + row];
  float idf = out[PIDX_BASE + row];
#pragma unroll
  for (int t = 1; t < 8; ++t) {
    const float ov = out[PVAL_BASE + (t << 15) + row];
    const float oif = out[PIDX_BASE + (t << 15) + row];
    if (ov < v) { v = ov; idf = oif; }  // strict <: earlier tile wins ties
  }
  out[IDX_OFF + row] = idf;
}

// ---------------- kernel C: z_q gather + loss ----------------
__global__ __launch_bounds__(256) void k_gather(const float* __restrict__ z,
                                                const float* __restrict__ emb,
                                                float* __restrict__ out) {
  const int tid = threadIdx.x;
  const int e0 = (blockIdx.x * 256 + tid) * 16;
  const int b = e0 >> 18;
  const int c = (e0 >> 10) & 255;
  const int n0 = (b << 10) + (e0 & 1023);
  float acc = 0.f;
#pragma unroll
  for (int g = 0; g < 4; ++g) {
    const float4 zv = *(const float4*)(z + e0 + g * 4);
    const float zz[4] = {zv.x, zv.y, zv.z, zv.w};
    float q[4];
#pragma unroll
    for (int j = 0; j < 4; ++j) {
      const int id = (int)(out[IDX_OFF + n0 + g * 4 + j] + 0.5f);
      const float e = emb[id * DDIM + c];
      q[j] = e;
      const float d = e - zz[j];
      acc = fmaf(d, d, acc);
    }
    const float4 qv = {q[0], q[1], q[2], q[3]};
    *(float4*)(out + e0 + g * 4) = qv;
  }
#pragma unroll
  for (int off = 32; off; off >>= 1) acc += __shfl_down(acc, off);
  __shared__ float sm[4];
  if ((tid & 63) == 0) sm[tid >> 6] = acc;
  __syncthreads();
  if (tid == 0)
    atomicAdd(out + LOSS_OFF,
              (sm[0] + sm[1] + sm[2] + sm[3]) * (1.25f / 8388608.0f));
}

extern "C" void kernel_launch(void* const* d_in, const int* in_sizes, int n_in,
                              void* d_out, int out_size, void* d_ws, size_t ws_size,
                              hipStream_t stream) {
  const float* z = (const float*)d_in[0];
  const float* emb = (const float*)d_in[1];
  float* out = (float*)d_out;

  k_enorm<<<256, 256, 0, stream>>>(emb, out);
  k_znorm<<<128, 256, 0, stream>>>(z, out);
  k_score<<<2048, 256, 0, stream>>>(z, emb, out);
  k_reduce<<<128, 256, 0, stream>>>(out);
  k_gather<<<2048, 256, 0, stream>>>(z, emb, out);
}